// Round 10
// baseline (468.830 us; speedup 1.0000x reference)
//
#include <hip/hip_runtime.h>

#define N_NODES 100000
#define N_EDGES 1600000
#define E_TOT   1700000
#define HID     128
#define NGRAPH  256
#define REPS    64

typedef unsigned short ushort_t;
typedef unsigned int uint_t;
typedef __attribute__((ext_vector_type(8))) short bf16x8;
typedef __attribute__((ext_vector_type(4))) float f32x4;

__device__ inline ushort_t f2bf(float f) {   // RNE pack
  uint_t u = __float_as_uint(f);
  return (ushort_t)((u + 0x7FFFu + ((u >> 16) & 1u)) >> 16);
}

// ---------------------------------------------------------------- CSR build
// 64-replica histogram: rank_local via atomic-return on replica (e&63).
// Per-(replica,address) contention = avg 0.27 (vs 17 single-table).
__global__ __launch_bounds__(256) void k_hist(const int* __restrict__ ei,
                                              int* __restrict__ cnt,
                                              int* __restrict__ rank) {
  const int nth = gridDim.x * 256;   // multiple of 64 -> (e & 63) == (tid & 63)
  const int tid = blockIdx.x * 256 + threadIdx.x;
  const int rep = tid & 63;
  int d[8], r[8];
#pragma unroll
  for (int u = 0; u < 8; ++u) {
    int e = tid + u * nth;
    d[u] = (e < E_TOT) ? ((e < N_EDGES) ? ei[N_EDGES + e] : (e - N_EDGES)) : -1;
  }
#pragma unroll
  for (int u = 0; u < 8; ++u)
    if (d[u] >= 0) r[u] = atomicAdd(&cnt[rep * N_NODES + d[u]], 1);
#pragma unroll
  for (int u = 0; u < 8; ++u)
    if (d[u] >= 0) rank[tid + u * nth] = r[u];
}

// per-node prefix over the 64 replicas; cnt becomes exclusive base; deg = total
__global__ __launch_bounds__(1024) void k_merge(int* __restrict__ cnt,
                                                int* __restrict__ deg) {
  int n = blockIdx.x * 1024 + threadIdx.x;
  if (n >= N_NODES) return;
  int run = 0;
#pragma unroll 8
  for (int k = 0; k < REPS; ++k) {
    int v = cnt[k * N_NODES + n];
    cnt[k * N_NODES + n] = run;
    run += v;
  }
  deg[n] = run;
}

__global__ __launch_bounds__(1024) void k_scan1(const int* __restrict__ deg,
                                                int* __restrict__ indptr,
                                                int* __restrict__ bsum) {
  __shared__ int sh[1024];
  int t = threadIdx.x;
  int i = blockIdx.x * 1024 + t;
  int v = (i < N_NODES) ? deg[i] : 0;
  sh[t] = v;
  __syncthreads();
  for (int off = 1; off < 1024; off <<= 1) {
    int x = (t >= off) ? sh[t - off] : 0;
    __syncthreads();
    sh[t] += x;
    __syncthreads();
  }
  if (i < N_NODES) indptr[i] = sh[t] - v;  // exclusive
  if (t == 1023) bsum[blockIdx.x] = sh[1023];
}

__global__ void k_scan2(const int* __restrict__ bsum, int* __restrict__ boff,
                        int* __restrict__ indptr, int nb) {
  if (threadIdx.x == 0 && blockIdx.x == 0) {
    int run = 0;
    for (int i = 0; i < nb; ++i) { boff[i] = run; run += bsum[i]; }
    indptr[N_NODES] = run;
  }
}

__global__ __launch_bounds__(1024) void k_scan3(int* __restrict__ indptr,
                                                const int* __restrict__ boff) {
  int i = blockIdx.x * 1024 + threadIdx.x;
  if (i < N_NODES) indptr[i] += boff[blockIdx.x];
}

// 16 edges per thread, no atomics: p = indptr[dst] + base[rep][dst] + rank[e]
__global__ __launch_bounds__(256) void k_scatter(const int* __restrict__ ei,
                                                 const int* __restrict__ indptr,
                                                 const int* __restrict__ rank,
                                                 const int* __restrict__ base,
                                                 int* __restrict__ csr_src) {
  const int nth = gridDim.x * 256;   // multiple of 64
  const int tid = blockIdx.x * 256 + threadIdx.x;
  const int rep = tid & 63;
  int src[16], dst[16], rk[16];
#pragma unroll
  for (int u = 0; u < 16; ++u) {
    int e = tid + u * nth;
    if (e < E_TOT) {
      if (e < N_EDGES) { src[u] = ei[e]; dst[u] = ei[N_EDGES + e]; }
      else             { src[u] = e - N_EDGES; dst[u] = src[u]; }
      rk[u] = rank[e];
    } else { src[u] = -1; dst[u] = 0; rk[u] = 0; }
  }
  int p[16];
#pragma unroll
  for (int u = 0; u < 16; ++u)
    if (src[u] >= 0)
      p[u] = indptr[dst[u]] + base[rep * N_NODES + dst[u]] + rk[u];
#pragma unroll
  for (int u = 0; u < 16; ++u)
    if (src[u] >= 0) csr_src[p[u]] = src[u];
}

// -------------------------------- MFMA GEMM h = X @ W^T (+ a_s/a_d), bf16 out
template <bool IN_F32>
__global__ __launch_bounds__(256) void k_gemm(const void* __restrict__ Xin,
                                              const float* __restrict__ W,
                                              const float* __restrict__ att_s,
                                              const float* __restrict__ att_d,
                                              ushort_t* __restrict__ Hb,
                                              float* __restrict__ As,
                                              float* __restrict__ Ad) {
  __shared__ ushort_t Wl[128 * 128];  // 32 KB
  __shared__ ushort_t Xl[64 * 128];   // 16 KB (reused as epilogue stage)
  const int t = threadIdx.x;
  const int row0 = blockIdx.x * 64;

#pragma unroll
  for (int i = 0; i < 16; ++i) {
    int idx = (t + i * 256) << 2;     // float index
    int o = idx >> 7, c = idx & 127;
    float4 w = *(const float4*)&W[idx];
    ushort4 wb{f2bf(w.x), f2bf(w.y), f2bf(w.z), f2bf(w.w)};
    *(ushort4*)((char*)Wl + o * 256 + ((c * 2) ^ ((o & 7) << 4))) = wb;
  }
  if (IN_F32) {
    const float* X = (const float*)Xin;
#pragma unroll
    for (int i = 0; i < 8; ++i) {
      int idx = (t + i * 256) << 2;
      int r = idx >> 7, c = idx & 127;
      int row = row0 + r;
      float4 xv = (row < N_NODES) ? *(const float4*)&X[row * 128 + c]
                                  : float4{0.f, 0.f, 0.f, 0.f};
      ushort4 xb{f2bf(xv.x), f2bf(xv.y), f2bf(xv.z), f2bf(xv.w)};
      *(ushort4*)((char*)Xl + r * 256 + ((c * 2) ^ ((r & 7) << 4))) = xb;
    }
  } else {
    const ushort_t* X = (const ushort_t*)Xin;
#pragma unroll
    for (int i = 0; i < 4; ++i) {
      int idx = (t + i * 256) << 3;   // ushort index, 8 per iter
      int r = idx >> 7, c = idx & 127;
      int row = row0 + r;
      uint4 xv = (row < N_NODES) ? *(const uint4*)&X[row * 128 + c]
                                 : uint4{0u, 0u, 0u, 0u};
      *(uint4*)((char*)Xl + r * 256 + ((c * 2) ^ ((r & 7) << 4))) = xv;
    }
  }
  __syncthreads();

  const int wv = t >> 6;
  const int lane = t & 63;
  const int lr = lane & 15;
  const int lg = lane >> 4;
  f32x4 acc[8] = {};

#pragma unroll
  for (int ks = 0; ks < 4; ++ks) {
    const int kbyte = ks * 64 + lg * 16;
    const int arow = wv * 16 + lr;
    bf16x8 afrag = *(const bf16x8*)((char*)Xl + arow * 256 +
                                    (kbyte ^ ((arow & 7) << 4)));
#pragma unroll
    for (int ot = 0; ot < 8; ++ot) {
      const int orow = ot * 16 + lr;
      bf16x8 bfrag = *(const bf16x8*)((char*)Wl + orow * 256 +
                                      (kbyte ^ ((orow & 7) << 4)));
      acc[ot] = __builtin_amdgcn_mfma_f32_16x16x32_bf16(afrag, bfrag, acc[ot],
                                                        0, 0, 0);
    }
  }

  // fused a_s/a_d epilogue
  float ps[4] = {0.f, 0.f, 0.f, 0.f}, pd[4] = {0.f, 0.f, 0.f, 0.f};
#pragma unroll
  for (int ot = 0; ot < 8; ++ot) {
    float sa = att_s[ot * 16 + lr], sd = att_d[ot * 16 + lr];
#pragma unroll
    for (int j = 0; j < 4; ++j) {
      ps[j] += acc[ot][j] * sa;
      pd[j] += acc[ot][j] * sd;
    }
  }
#pragma unroll
  for (int m = 1; m < 16; m <<= 1) {
#pragma unroll
    for (int j = 0; j < 4; ++j) {
      ps[j] += __shfl_xor(ps[j], m);
      pd[j] += __shfl_xor(pd[j], m);
    }
  }
  if (lr == 0) {
#pragma unroll
    for (int j = 0; j < 4; ++j) {
      int row = row0 + wv * 16 + lg * 4 + j;
      if (row < N_NODES) { As[row] = ps[j]; Ad[row] = pd[j]; }
    }
  }

  // stage D tile (bf16, swizzled) in Xl, then coalesced write
  __syncthreads();
#pragma unroll
  for (int ot = 0; ot < 8; ++ot)
#pragma unroll
    for (int j = 0; j < 4; ++j) {
      int r = wv * 16 + lg * 4 + j;
      int cbyte = (ot * 16 + lr) * 2;
      *(ushort_t*)((char*)Xl + r * 256 + (cbyte ^ ((r & 7) << 4))) =
          f2bf(acc[ot][j]);
    }
  __syncthreads();
#pragma unroll
  for (int i = 0; i < 4; ++i) {
    int idx = t + i * 256;
    int r = idx >> 4, u = idx & 15;
    int row = row0 + r;
    if (row < N_NODES)
      *(uint4*)&Hb[row * 128 + u * 8] =
          *(const uint4*)((char*)Xl + r * 256 + ((u * 16) ^ ((r & 7) << 4)));
  }
}

// ------------------------------------- attention softmax + aggregation (CSR)
// TWO nodes per wave (R9 structure, unchanged)
__global__ __launch_bounds__(256) void k_agg(const ushort_t* __restrict__ Hb,
                                             const float* __restrict__ a_s,
                                             const float* __restrict__ a_d,
                                             const int* __restrict__ indptr,
                                             const int* __restrict__ csr_src,
                                             const float* __restrict__ bias,
                                             ushort_t* __restrict__ OUTb) {
  const int lane = threadIdx.x & 63;
  const int wid  = threadIdx.x >> 6;
  const int half = lane >> 5;
  const int l32  = lane & 31;
  const int n = blockIdx.x * 8 + wid * 2 + half;

  const int start = indptr[n];
  const int deg   = indptr[n + 1] - start;
  const float adn = a_d[n];

  int   s0 = csr_src[start + ((l32 < deg) ? l32 : 0)];
  float e0 = -1e30f;
  if (l32 < deg) {
    float e = a_s[s0] + adn;
    e0 = (e > 0.f) ? e : 0.2f * e;
  }
  float lmax = e0;
  for (int j = l32 + 32; j < deg; j += 32) {
    float e = a_s[csr_src[start + j]] + adn;
    e = (e > 0.f) ? e : 0.2f * e;
    lmax = fmaxf(lmax, e);
  }
#pragma unroll
  for (int m = 1; m < 32; m <<= 1) lmax = fmaxf(lmax, __shfl_xor(lmax, m));

  float ex0 = (l32 < deg) ? __expf(e0 - lmax) : 0.f;
  float lsum = ex0;
  for (int j = l32 + 32; j < deg; j += 32) {
    float e = a_s[csr_src[start + j]] + adn;
    e = (e > 0.f) ? e : 0.2f * e;
    lsum += __expf(e - lmax);
  }
#pragma unroll
  for (int m = 1; m < 32; m <<= 1) lsum += __shfl_xor(lsum, m);
  const float inv = 1.0f / lsum;

  const int degA = __shfl(deg, 0);
  const int degB = __shfl(deg, 32);
  const int degM = max(degA, degB);

  const int q  = lane >> 4;
  const int qe = q & 1;
  const int srcbase = (q >> 1) << 5;
  const int ch = (lane & 15) << 3;
  float acc8[8] = {0.f, 0.f, 0.f, 0.f, 0.f, 0.f, 0.f, 0.f};

#define FMA8(W4, A)                                                         \
  {                                                                         \
    float a_ = (A);                                                         \
    acc8[0] += a_ * __uint_as_float((W4).x << 16);                          \
    acc8[1] += a_ * __uint_as_float((W4).x & 0xFFFF0000u);                  \
    acc8[2] += a_ * __uint_as_float((W4).y << 16);                          \
    acc8[3] += a_ * __uint_as_float((W4).y & 0xFFFF0000u);                  \
    acc8[4] += a_ * __uint_as_float((W4).z << 16);                          \
    acc8[5] += a_ * __uint_as_float((W4).z & 0xFFFF0000u);                  \
    acc8[6] += a_ * __uint_as_float((W4).w << 16);                          \
    acc8[7] += a_ * __uint_as_float((W4).w & 0xFFFF0000u);                  \
  }

  for (int base = 0; base < degM; base += 32) {
    float myal;
    int mys;
    if (base == 0) {
      myal = ex0 * inv;
      mys = s0;
    } else {
      int j = base + l32;
      mys = csr_src[start + ((j < deg) ? j : 0)];
      myal = 0.f;
      if (j < deg) {
        float e = a_s[mys] + adn;
        e = (e > 0.f) ? e : 0.2f * e;
        myal = __expf(e - lmax) * inv;
      }
    }
    const int npM = (min(degM - base, 32) + 1) >> 1;
    int u0 = 0;
    for (; u0 + 4 <= npM; u0 += 4) {
      float av[4]; int sv[4]; uint4 hv[4];
#pragma unroll
      for (int u = 0; u < 4; ++u) {
        int sl = srcbase + (((u0 + u) << 1) + qe);
        av[u] = __shfl(myal, sl);
        sv[u] = __shfl(mys, sl);
      }
#pragma unroll
      for (int u = 0; u < 4; ++u)
        hv[u] = *(const uint4*)&Hb[sv[u] * 128 + ch];
#pragma unroll
      for (int u = 0; u < 4; ++u) FMA8(hv[u], av[u]);
    }
    for (; u0 < npM; ++u0) {
      int sl = srcbase + ((u0 << 1) + qe);
      float a = __shfl(myal, sl);
      int s = __shfl(mys, sl);
      uint4 hv = *(const uint4*)&Hb[s * 128 + ch];
      FMA8(hv, a);
    }
  }
#undef FMA8

#pragma unroll
  for (int c = 0; c < 8; ++c) acc8[c] += __shfl_xor(acc8[c], 16);

  if (qe == 0) {
    float4 b0 = *(const float4*)&bias[ch];
    float4 b1 = *(const float4*)&bias[ch + 4];
    ushort4 lo{f2bf(fmaxf(acc8[0] + b0.x, 0.f)),
               f2bf(fmaxf(acc8[1] + b0.y, 0.f)),
               f2bf(fmaxf(acc8[2] + b0.z, 0.f)),
               f2bf(fmaxf(acc8[3] + b0.w, 0.f))};
    ushort4 hi{f2bf(fmaxf(acc8[4] + b1.x, 0.f)),
               f2bf(fmaxf(acc8[5] + b1.y, 0.f)),
               f2bf(fmaxf(acc8[6] + b1.z, 0.f)),
               f2bf(fmaxf(acc8[7] + b1.w, 0.f))};
    *(ushort4*)&OUTb[n * 128 + ch] = lo;
    *(ushort4*)&OUTb[n * 128 + ch + 4] = hi;
  }
}

// ---------------------------------------------- head (128->8, tanh), bf16 in
__global__ __launch_bounds__(256) void k_head(const ushort_t* __restrict__ Hb,
                                              const float* __restrict__ Wl,
                                              const float* __restrict__ bl,
                                              float* __restrict__ h8) {
  __shared__ float Wls[8][128];
  int t = threadIdx.x;
#pragma unroll
  for (int i = 0; i < 4; ++i) {
    int idx = t + i * 256;
    Wls[idx >> 7][idx & 127] = Wl[idx];
  }
  __syncthreads();

  int n = blockIdx.x * 4 + (t >> 6);
  if (n >= N_NODES) return;
  int lane = t & 63;
  uint_t hv = *(const uint_t*)&Hb[n * 128 + 2 * lane];
  float hx = __uint_as_float((hv & 0xFFFFu) << 16);
  float hy = __uint_as_float(hv & 0xFFFF0000u);
  float mine = 0.f;
#pragma unroll
  for (int a = 0; a < 8; ++a) {
    float2 wv = *(const float2*)&Wls[a][2 * lane];
    float v = hx * wv.x + hy * wv.y;
#pragma unroll
    for (int m = 1; m < 64; m <<= 1) v += __shfl_xor(v, m);
    if (lane == a) mine = v;
  }
  if (lane < 8) h8[n * 8 + lane] = tanhf(mine + bl[lane]);
}

// ------------------------------------ mean pool: one block per graph
__global__ __launch_bounds__(256) void k_pool(const float* __restrict__ h8,
                                              const int* __restrict__ batch,
                                              float* __restrict__ out) {
  int g = blockIdx.x;
  __shared__ int bounds[2];
  if (threadIdx.x < 2) {
    int target = g + threadIdx.x;
    int lo = 0, hi = N_NODES;
    while (lo < hi) {
      int mid = (lo + hi) >> 1;
      if (batch[mid] < target) lo = mid + 1; else hi = mid;
    }
    bounds[threadIdx.x] = lo;
  }
  __syncthreads();
  int lo = bounds[0], hi = bounds[1];
  int ch = threadIdx.x & 7;
  float acc = 0.f;
  for (int n = lo + (threadIdx.x >> 3); n < hi; n += 32)
    acc += h8[n * 8 + ch];

  __shared__ float red[256];
  red[threadIdx.x] = acc;
  __syncthreads();
  for (int off = 128; off >= 8; off >>= 1) {
    if (threadIdx.x < off) red[threadIdx.x] += red[threadIdx.x + off];
    __syncthreads();
  }
  if (threadIdx.x < 8)
    out[g * 8 + threadIdx.x] = red[threadIdx.x] / fmaxf((float)(hi - lo), 1.0f);
}

// ---------------------------------------------------------------- launcher
extern "C" void kernel_launch(void* const* d_in, const int* in_sizes, int n_in,
                              void* d_out, int out_size, void* d_ws, size_t ws_size,
                              hipStream_t stream) {
  const float* x   = (const float*)d_in[0];
  const int*   ei  = (const int*)d_in[1];
  const int*   bat = (const int*)d_in[2];
  const float* Wm[3]  = {(const float*)d_in[3],  (const float*)d_in[7],  (const float*)d_in[11]};
  const float* asv[3] = {(const float*)d_in[4],  (const float*)d_in[8],  (const float*)d_in[12]};
  const float* adv[3] = {(const float*)d_in[5],  (const float*)d_in[9],  (const float*)d_in[13]};
  const float* bv[3]  = {(const float*)d_in[6],  (const float*)d_in[10], (const float*)d_in[14]};
  const float* Wl  = (const float*)d_in[15];
  const float* bl  = (const float*)d_in[16];
  float* out = (float*)d_out;

  char* w = (char*)d_ws;
  ushort_t* Hb   = (ushort_t*)(w + 0);         // 25,600,000 B (gemm out, bf16)
  ushort_t* hB2  = (ushort_t*)(w + 25600000);  // 25,600,000 B (agg out, bf16)
  float* a_s     = (float*)(w + 51200000);     // 400,000 B
  float* a_d     = (float*)(w + 51600000);     // 400,000 B
  int*   deg     = (int*)  (w + 52000000);     // 400,000 B
  int*   indptr  = (int*)  (w + 52400000);     // 400,128 B
  int*   bsum    = (int*)  (w + 52800128);     // 512 B
  int*   boff    = (int*)  (w + 52800640);     // 512 B
  int*   csr     = (int*)  (w + 52801152);     // 6,800,000 B
  int*   rankb   = (int*)  (w + 59601152);     // 6,800,000 B
  float* h8      = (float*)(w + 66401152);     // 3,200,000 B
  int*   cnt     = (int*)  (w + 69601152);     // 25,600,000 B (64-replica hist)

  hipMemsetAsync(cnt, 0, REPS * N_NODES * sizeof(int), stream);

  const int gblk = (N_NODES + 63) / 64;
  const int ablk = N_NODES / 8;   // 2 nodes per wave, 8 per block

  k_gemm<true><<<gblk, 256, 0, stream>>>(x, Wm[0], asv[0], adv[0], Hb, a_s, a_d);
  k_hist   <<<831, 256, 0, stream>>>(ei, cnt, rankb);
  k_merge  <<<98, 1024, 0, stream>>>(cnt, deg);
  k_scan1  <<<98, 1024, 0, stream>>>(deg, indptr, bsum);
  k_scan2  <<<1, 64, 0, stream>>>(bsum, boff, indptr, 98);
  k_scan3  <<<98, 1024, 0, stream>>>(indptr, boff);
  k_scatter<<<416, 256, 0, stream>>>(ei, indptr, rankb, cnt, csr);

  k_agg<<<ablk, 256, 0, stream>>>(Hb, a_s, a_d, indptr, csr, bv[0], hB2);
  for (int l = 1; l < 3; ++l) {
    k_gemm<false><<<gblk, 256, 0, stream>>>(hB2, Wm[l], asv[l], adv[l], Hb,
                                            a_s, a_d);
    k_agg<<<ablk, 256, 0, stream>>>(Hb, a_s, a_d, indptr, csr, bv[l], hB2);
  }

  k_head<<<N_NODES / 4, 256, 0, stream>>>(hB2, Wl, bl, h8);
  k_pool<<<NGRAPH, 256, 0, stream>>>(h8, bat, out);
}

// Round 11
// 368.804 us; speedup vs baseline: 1.2712x; 1.2712x over previous
//
#include <hip/hip_runtime.h>

#define N_NODES 100000
#define N_EDGES 1600000
#define E_TOT   1700000
#define HID     128
#define NGRAPH  256
#define NBUCK   196      // ceil(100000/512)
#define NBLK1   831      // ceil(1700000/2048)
#define HSTRIDE 832

typedef unsigned short ushort_t;
typedef unsigned int uint_t;
typedef __attribute__((ext_vector_type(8))) short bf16x8;
typedef __attribute__((ext_vector_type(4))) float f32x4;

__device__ inline ushort_t f2bf(float f) {   // RNE pack
  uint_t u = __float_as_uint(f);
  return (ushort_t)((u + 0x7FFFu + ((u >> 16) & 1u)) >> 16);
}

// --------------------------- CSR build: 2-level LDS bucket sort, no global atomics
// level 1: 196 buckets (dst>>9); per-block histogram
__global__ __launch_bounds__(256) void k_b1(const int* __restrict__ ei,
                                            int* __restrict__ hist) {
  __shared__ int h[NBUCK];
  const int t = threadIdx.x;
  for (int i = t; i < NBUCK; i += 256) h[i] = 0;
  __syncthreads();
  const int e0 = blockIdx.x * 2048;
#pragma unroll
  for (int u = 0; u < 8; ++u) {
    int e = e0 + u * 256 + t;
    if (e < E_TOT) {
      int dst = (e < N_EDGES) ? ei[N_EDGES + e] : (e - N_EDGES);
      atomicAdd(&h[dst >> 9], 1);
    }
  }
  __syncthreads();
  for (int i = t; i < NBUCK; i += 256) hist[i * HSTRIDE + blockIdx.x] = h[i];
}

// per-bucket exclusive scan across the 831 blocks
__global__ __launch_bounds__(1024) void k_bscan1(int* __restrict__ hist,
                                                 int* __restrict__ btot) {
  __shared__ int sh[1024];
  const int b = blockIdx.x, t = threadIdx.x;
  int v = (t < NBLK1) ? hist[b * HSTRIDE + t] : 0;
  sh[t] = v;
  __syncthreads();
  for (int off = 1; off < 1024; off <<= 1) {
    int x = (t >= off) ? sh[t - off] : 0;
    __syncthreads();
    sh[t] += x;
    __syncthreads();
  }
  if (t < NBLK1) hist[b * HSTRIDE + t] = sh[t] - v;   // exclusive
  if (t == 1023) btot[b] = sh[1023];
}

// bucket bases (exclusive scan of 196 totals)
__global__ void k_bscan2(const int* __restrict__ btot, int* __restrict__ bbase) {
  if (threadIdx.x == 0 && blockIdx.x == 0) {
    int run = 0;
    for (int i = 0; i < NBUCK; ++i) { bbase[i] = run; run += btot[i]; }
    bbase[NBUCK] = run;   // == E_TOT
  }
}

// scatter edges into bucket-grouped buf (rank via LDS atomic-return)
__global__ __launch_bounds__(256) void k_b2(const int* __restrict__ ei,
                                            const int* __restrict__ hist,
                                            const int* __restrict__ bbase,
                                            int2* __restrict__ buf) {
  __shared__ int h[NBUCK];
  __shared__ int base2[NBUCK];
  const int t = threadIdx.x;
  for (int i = t; i < NBUCK; i += 256) {
    h[i] = 0;
    base2[i] = bbase[i] + hist[i * HSTRIDE + blockIdx.x];
  }
  __syncthreads();
  const int e0 = blockIdx.x * 2048;
#pragma unroll
  for (int u = 0; u < 8; ++u) {
    int e = e0 + u * 256 + t;
    if (e < E_TOT) {
      int src, dst;
      if (e < N_EDGES) { src = ei[e]; dst = ei[N_EDGES + e]; }
      else             { src = e - N_EDGES; dst = src; }
      int bk = dst >> 9;
      int r = atomicAdd(&h[bk], 1);
      buf[base2[bk] + r] = int2{src, dst};
    }
  }
}

// finalize: one block per bucket -> indptr + csr_src (cursor method)
__global__ __launch_bounds__(512) void k_b3(const int2* __restrict__ buf,
                                            const int* __restrict__ bbase,
                                            int* __restrict__ indptr,
                                            int* __restrict__ csr_src) {
  __shared__ int cnt[512];
  __shared__ int cur[512];
  const int b = blockIdx.x, t = threadIdx.x;
  cnt[t] = 0;
  __syncthreads();
  const int es = bbase[b], ee = bbase[b + 1];
  for (int e = es + t; e < ee; e += 512) {
    int2 p = buf[e];
    atomicAdd(&cnt[p.y & 511], 1);
  }
  __syncthreads();
  // exclusive scan of cnt -> cursor (absolute positions)
  int v = cnt[t];
  cur[t] = v;
  __syncthreads();
  for (int off = 1; off < 512; off <<= 1) {
    int x = (t >= off) ? cur[t - off] : 0;
    __syncthreads();
    cur[t] += x;
    __syncthreads();
  }
  int excl = cur[t] - v;
  int n = b * 512 + t;
  if (n < N_NODES) indptr[n] = es + excl;
  if (b == NBUCK - 1 && t == 0) indptr[N_NODES] = E_TOT;
  __syncthreads();
  cur[t] = es + excl;       // running cursor
  __syncthreads();
  for (int e = es + t; e < ee; e += 512) {
    int2 p = buf[e];
    int pos = atomicAdd(&cur[p.y & 511], 1);
    csr_src[pos] = p.x;
  }
}

// -------------------------------- MFMA GEMM h = X @ W^T (+ a_s/a_d), bf16 out
template <bool IN_F32>
__global__ __launch_bounds__(256) void k_gemm(const void* __restrict__ Xin,
                                              const float* __restrict__ W,
                                              const float* __restrict__ att_s,
                                              const float* __restrict__ att_d,
                                              ushort_t* __restrict__ Hb,
                                              float* __restrict__ As,
                                              float* __restrict__ Ad) {
  __shared__ ushort_t Wl[128 * 128];  // 32 KB
  __shared__ ushort_t Xl[64 * 128];   // 16 KB (reused as epilogue stage)
  const int t = threadIdx.x;
  const int row0 = blockIdx.x * 64;

#pragma unroll
  for (int i = 0; i < 16; ++i) {
    int idx = (t + i * 256) << 2;     // float index
    int o = idx >> 7, c = idx & 127;
    float4 w = *(const float4*)&W[idx];
    ushort4 wb{f2bf(w.x), f2bf(w.y), f2bf(w.z), f2bf(w.w)};
    *(ushort4*)((char*)Wl + o * 256 + ((c * 2) ^ ((o & 7) << 4))) = wb;
  }
  if (IN_F32) {
    const float* X = (const float*)Xin;
#pragma unroll
    for (int i = 0; i < 8; ++i) {
      int idx = (t + i * 256) << 2;
      int r = idx >> 7, c = idx & 127;
      int row = row0 + r;
      float4 xv = (row < N_NODES) ? *(const float4*)&X[row * 128 + c]
                                  : float4{0.f, 0.f, 0.f, 0.f};
      ushort4 xb{f2bf(xv.x), f2bf(xv.y), f2bf(xv.z), f2bf(xv.w)};
      *(ushort4*)((char*)Xl + r * 256 + ((c * 2) ^ ((r & 7) << 4))) = xb;
    }
  } else {
    const ushort_t* X = (const ushort_t*)Xin;
#pragma unroll
    for (int i = 0; i < 4; ++i) {
      int idx = (t + i * 256) << 3;   // ushort index, 8 per iter
      int r = idx >> 7, c = idx & 127;
      int row = row0 + r;
      uint4 xv = (row < N_NODES) ? *(const uint4*)&X[row * 128 + c]
                                 : uint4{0u, 0u, 0u, 0u};
      *(uint4*)((char*)Xl + r * 256 + ((c * 2) ^ ((r & 7) << 4))) = xv;
    }
  }
  __syncthreads();

  const int wv = t >> 6;
  const int lane = t & 63;
  const int lr = lane & 15;
  const int lg = lane >> 4;
  f32x4 acc[8] = {};

#pragma unroll
  for (int ks = 0; ks < 4; ++ks) {
    const int kbyte = ks * 64 + lg * 16;
    const int arow = wv * 16 + lr;
    bf16x8 afrag = *(const bf16x8*)((char*)Xl + arow * 256 +
                                    (kbyte ^ ((arow & 7) << 4)));
#pragma unroll
    for (int ot = 0; ot < 8; ++ot) {
      const int orow = ot * 16 + lr;
      bf16x8 bfrag = *(const bf16x8*)((char*)Wl + orow * 256 +
                                      (kbyte ^ ((orow & 7) << 4)));
      acc[ot] = __builtin_amdgcn_mfma_f32_16x16x32_bf16(afrag, bfrag, acc[ot],
                                                        0, 0, 0);
    }
  }

  // fused a_s/a_d epilogue
  float ps[4] = {0.f, 0.f, 0.f, 0.f}, pd[4] = {0.f, 0.f, 0.f, 0.f};
#pragma unroll
  for (int ot = 0; ot < 8; ++ot) {
    float sa = att_s[ot * 16 + lr], sd = att_d[ot * 16 + lr];
#pragma unroll
    for (int j = 0; j < 4; ++j) {
      ps[j] += acc[ot][j] * sa;
      pd[j] += acc[ot][j] * sd;
    }
  }
#pragma unroll
  for (int m = 1; m < 16; m <<= 1) {
#pragma unroll
    for (int j = 0; j < 4; ++j) {
      ps[j] += __shfl_xor(ps[j], m);
      pd[j] += __shfl_xor(pd[j], m);
    }
  }
  if (lr == 0) {
#pragma unroll
    for (int j = 0; j < 4; ++j) {
      int row = row0 + wv * 16 + lg * 4 + j;
      if (row < N_NODES) { As[row] = ps[j]; Ad[row] = pd[j]; }
    }
  }

  // stage D tile (bf16, swizzled) in Xl, then coalesced write
  __syncthreads();
#pragma unroll
  for (int ot = 0; ot < 8; ++ot)
#pragma unroll
    for (int j = 0; j < 4; ++j) {
      int r = wv * 16 + lg * 4 + j;
      int cbyte = (ot * 16 + lr) * 2;
      *(ushort_t*)((char*)Xl + r * 256 + (cbyte ^ ((r & 7) << 4))) =
          f2bf(acc[ot][j]);
    }
  __syncthreads();
#pragma unroll
  for (int i = 0; i < 4; ++i) {
    int idx = t + i * 256;
    int r = idx >> 4, u = idx & 15;
    int row = row0 + r;
    if (row < N_NODES)
      *(uint4*)&Hb[row * 128 + u * 8] =
          *(const uint4*)((char*)Xl + r * 256 + ((u * 16) ^ ((r & 7) << 4)));
  }
}

// ------------------------------------- attention softmax + aggregation (CSR)
// TWO nodes per wave (R9 structure, unchanged)
__global__ __launch_bounds__(256) void k_agg(const ushort_t* __restrict__ Hb,
                                             const float* __restrict__ a_s,
                                             const float* __restrict__ a_d,
                                             const int* __restrict__ indptr,
                                             const int* __restrict__ csr_src,
                                             const float* __restrict__ bias,
                                             ushort_t* __restrict__ OUTb) {
  const int lane = threadIdx.x & 63;
  const int wid  = threadIdx.x >> 6;
  const int half = lane >> 5;
  const int l32  = lane & 31;
  const int n = blockIdx.x * 8 + wid * 2 + half;

  const int start = indptr[n];
  const int deg   = indptr[n + 1] - start;
  const float adn = a_d[n];

  int   s0 = csr_src[start + ((l32 < deg) ? l32 : 0)];
  float e0 = -1e30f;
  if (l32 < deg) {
    float e = a_s[s0] + adn;
    e0 = (e > 0.f) ? e : 0.2f * e;
  }
  float lmax = e0;
  for (int j = l32 + 32; j < deg; j += 32) {
    float e = a_s[csr_src[start + j]] + adn;
    e = (e > 0.f) ? e : 0.2f * e;
    lmax = fmaxf(lmax, e);
  }
#pragma unroll
  for (int m = 1; m < 32; m <<= 1) lmax = fmaxf(lmax, __shfl_xor(lmax, m));

  float ex0 = (l32 < deg) ? __expf(e0 - lmax) : 0.f;
  float lsum = ex0;
  for (int j = l32 + 32; j < deg; j += 32) {
    float e = a_s[csr_src[start + j]] + adn;
    e = (e > 0.f) ? e : 0.2f * e;
    lsum += __expf(e - lmax);
  }
#pragma unroll
  for (int m = 1; m < 32; m <<= 1) lsum += __shfl_xor(lsum, m);
  const float inv = 1.0f / lsum;

  const int degA = __shfl(deg, 0);
  const int degB = __shfl(deg, 32);
  const int degM = max(degA, degB);

  const int q  = lane >> 4;
  const int qe = q & 1;
  const int srcbase = (q >> 1) << 5;
  const int ch = (lane & 15) << 3;
  float acc8[8] = {0.f, 0.f, 0.f, 0.f, 0.f, 0.f, 0.f, 0.f};

#define FMA8(W4, A)                                                         \
  {                                                                         \
    float a_ = (A);                                                         \
    acc8[0] += a_ * __uint_as_float((W4).x << 16);                          \
    acc8[1] += a_ * __uint_as_float((W4).x & 0xFFFF0000u);                  \
    acc8[2] += a_ * __uint_as_float((W4).y << 16);                          \
    acc8[3] += a_ * __uint_as_float((W4).y & 0xFFFF0000u);                  \
    acc8[4] += a_ * __uint_as_float((W4).z << 16);                          \
    acc8[5] += a_ * __uint_as_float((W4).z & 0xFFFF0000u);                  \
    acc8[6] += a_ * __uint_as_float((W4).w << 16);                          \
    acc8[7] += a_ * __uint_as_float((W4).w & 0xFFFF0000u);                  \
  }

  for (int base = 0; base < degM; base += 32) {
    float myal;
    int mys;
    if (base == 0) {
      myal = ex0 * inv;
      mys = s0;
    } else {
      int j = base + l32;
      mys = csr_src[start + ((j < deg) ? j : 0)];
      myal = 0.f;
      if (j < deg) {
        float e = a_s[mys] + adn;
        e = (e > 0.f) ? e : 0.2f * e;
        myal = __expf(e - lmax) * inv;
      }
    }
    const int npM = (min(degM - base, 32) + 1) >> 1;
    int u0 = 0;
    for (; u0 + 4 <= npM; u0 += 4) {
      float av[4]; int sv[4]; uint4 hv[4];
#pragma unroll
      for (int u = 0; u < 4; ++u) {
        int sl = srcbase + (((u0 + u) << 1) + qe);
        av[u] = __shfl(myal, sl);
        sv[u] = __shfl(mys, sl);
      }
#pragma unroll
      for (int u = 0; u < 4; ++u)
        hv[u] = *(const uint4*)&Hb[sv[u] * 128 + ch];
#pragma unroll
      for (int u = 0; u < 4; ++u) FMA8(hv[u], av[u]);
    }
    for (; u0 < npM; ++u0) {
      int sl = srcbase + ((u0 << 1) + qe);
      float a = __shfl(myal, sl);
      int s = __shfl(mys, sl);
      uint4 hv = *(const uint4*)&Hb[s * 128 + ch];
      FMA8(hv, a);
    }
  }
#undef FMA8

#pragma unroll
  for (int c = 0; c < 8; ++c) acc8[c] += __shfl_xor(acc8[c], 16);

  if (qe == 0) {
    float4 b0 = *(const float4*)&bias[ch];
    float4 b1 = *(const float4*)&bias[ch + 4];
    ushort4 lo{f2bf(fmaxf(acc8[0] + b0.x, 0.f)),
               f2bf(fmaxf(acc8[1] + b0.y, 0.f)),
               f2bf(fmaxf(acc8[2] + b0.z, 0.f)),
               f2bf(fmaxf(acc8[3] + b0.w, 0.f))};
    ushort4 hi{f2bf(fmaxf(acc8[4] + b1.x, 0.f)),
               f2bf(fmaxf(acc8[5] + b1.y, 0.f)),
               f2bf(fmaxf(acc8[6] + b1.z, 0.f)),
               f2bf(fmaxf(acc8[7] + b1.w, 0.f))};
    *(ushort4*)&OUTb[n * 128 + ch] = lo;
    *(ushort4*)&OUTb[n * 128 + ch + 4] = hi;
  }
}

// ---------------------------------------------- head (128->8, tanh), bf16 in
__global__ __launch_bounds__(256) void k_head(const ushort_t* __restrict__ Hb,
                                              const float* __restrict__ Wl,
                                              const float* __restrict__ bl,
                                              float* __restrict__ h8) {
  __shared__ float Wls[8][128];
  int t = threadIdx.x;
#pragma unroll
  for (int i = 0; i < 4; ++i) {
    int idx = t + i * 256;
    Wls[idx >> 7][idx & 127] = Wl[idx];
  }
  __syncthreads();

  int n = blockIdx.x * 4 + (t >> 6);
  if (n >= N_NODES) return;
  int lane = t & 63;
  uint_t hv = *(const uint_t*)&Hb[n * 128 + 2 * lane];
  float hx = __uint_as_float((hv & 0xFFFFu) << 16);
  float hy = __uint_as_float(hv & 0xFFFF0000u);
  float mine = 0.f;
#pragma unroll
  for (int a = 0; a < 8; ++a) {
    float2 wv = *(const float2*)&Wls[a][2 * lane];
    float v = hx * wv.x + hy * wv.y;
#pragma unroll
    for (int m = 1; m < 64; m <<= 1) v += __shfl_xor(v, m);
    if (lane == a) mine = v;
  }
  if (lane < 8) h8[n * 8 + lane] = tanhf(mine + bl[lane]);
}

// ------------------------------------ mean pool: one block per graph
__global__ __launch_bounds__(256) void k_pool(const float* __restrict__ h8,
                                              const int* __restrict__ batch,
                                              float* __restrict__ out) {
  int g = blockIdx.x;
  __shared__ int bounds[2];
  if (threadIdx.x < 2) {
    int target = g + threadIdx.x;
    int lo = 0, hi = N_NODES;
    while (lo < hi) {
      int mid = (lo + hi) >> 1;
      if (batch[mid] < target) lo = mid + 1; else hi = mid;
    }
    bounds[threadIdx.x] = lo;
  }
  __syncthreads();
  int lo = bounds[0], hi = bounds[1];
  int ch = threadIdx.x & 7;
  float acc = 0.f;
  for (int n = lo + (threadIdx.x >> 3); n < hi; n += 32)
    acc += h8[n * 8 + ch];

  __shared__ float red[256];
  red[threadIdx.x] = acc;
  __syncthreads();
  for (int off = 128; off >= 8; off >>= 1) {
    if (threadIdx.x < off) red[threadIdx.x] += red[threadIdx.x + off];
    __syncthreads();
  }
  if (threadIdx.x < 8)
    out[g * 8 + threadIdx.x] = red[threadIdx.x] / fmaxf((float)(hi - lo), 1.0f);
}

// ---------------------------------------------------------------- launcher
extern "C" void kernel_launch(void* const* d_in, const int* in_sizes, int n_in,
                              void* d_out, int out_size, void* d_ws, size_t ws_size,
                              hipStream_t stream) {
  const float* x   = (const float*)d_in[0];
  const int*   ei  = (const int*)d_in[1];
  const int*   bat = (const int*)d_in[2];
  const float* Wm[3]  = {(const float*)d_in[3],  (const float*)d_in[7],  (const float*)d_in[11]};
  const float* asv[3] = {(const float*)d_in[4],  (const float*)d_in[8],  (const float*)d_in[12]};
  const float* adv[3] = {(const float*)d_in[5],  (const float*)d_in[9],  (const float*)d_in[13]};
  const float* bv[3]  = {(const float*)d_in[6],  (const float*)d_in[10], (const float*)d_in[14]};
  const float* Wl  = (const float*)d_in[15];
  const float* bl  = (const float*)d_in[16];
  float* out = (float*)d_out;

  char* w = (char*)d_ws;
  ushort_t* Hb   = (ushort_t*)(w + 0);         // 25,600,000 B (gemm out, bf16)
  ushort_t* hB2  = (ushort_t*)(w + 25600000);  // 25,600,000 B (agg out, bf16)
  float* a_s     = (float*)(w + 51200000);     // 400,000 B
  float* a_d     = (float*)(w + 51600000);     // 400,000 B
  int*   indptr  = (int*)  (w + 52000000);     // 400,128 B
  int*   csr     = (int*)  (w + 52400128);     // 6,800,000 B
  int2*  buf1    = (int2*) (w + 59200128);     // 13,600,000 B
  int*   hist    = (int*)  (w + 72800128);     // 652,288 B (196 x 832)
  int*   btot    = (int*)  (w + 73452416);     // 784 B
  int*   bbase   = (int*)  (w + 73453200);     // 788 B
  float* h8      = (float*)(w + 73454000);     // 3,200,000 B

  const int gblk = (N_NODES + 63) / 64;
  const int ablk = N_NODES / 8;   // 2 nodes per wave, 8 per block

  // CSR build (bucket sort, LDS atomics only)
  k_b1    <<<NBLK1, 256, 0, stream>>>(ei, hist);
  k_bscan1<<<NBUCK, 1024, 0, stream>>>(hist, btot);
  k_bscan2<<<1, 64, 0, stream>>>(btot, bbase);
  k_b2    <<<NBLK1, 256, 0, stream>>>(ei, hist, bbase, buf1);
  k_b3    <<<NBUCK, 512, 0, stream>>>(buf1, bbase, indptr, csr);

  k_gemm<true><<<gblk, 256, 0, stream>>>(x, Wm[0], asv[0], adv[0], Hb, a_s, a_d);
  k_agg<<<ablk, 256, 0, stream>>>(Hb, a_s, a_d, indptr, csr, bv[0], hB2);
  for (int l = 1; l < 3; ++l) {
    k_gemm<false><<<gblk, 256, 0, stream>>>(hB2, Wm[l], asv[l], adv[l], Hb,
                                            a_s, a_d);
    k_agg<<<ablk, 256, 0, stream>>>(Hb, a_s, a_d, indptr, csr, bv[l], hB2);
  }

  k_head<<<N_NODES / 4, 256, 0, stream>>>(hB2, Wl, bl, h8);
  k_pool<<<NGRAPH, 256, 0, stream>>>(h8, bat, out);
}

// Round 12
// 363.214 us; speedup vs baseline: 1.2908x; 1.0154x over previous
//
#include <hip/hip_runtime.h>

#define N_NODES 100000
#define N_EDGES 1600000
#define E_TOT   1700000
#define HID     128
#define NGRAPH  256
#define NBUCK   196      // ceil(100000/512)
#define NBLK1   831      // ceil(1700000/2048)
#define HSTRIDE 832

typedef unsigned short ushort_t;
typedef unsigned int uint_t;
typedef __attribute__((ext_vector_type(8))) short bf16x8;
typedef __attribute__((ext_vector_type(4))) float f32x4;

__device__ inline ushort_t f2bf(float f) {   // RNE pack
  uint_t u = __float_as_uint(f);
  return (ushort_t)((u + 0x7FFFu + ((u >> 16) & 1u)) >> 16);
}

// --------------------------- CSR build: 2-level LDS bucket sort, no global atomics
__global__ __launch_bounds__(256) void k_b1(const int* __restrict__ ei,
                                            int* __restrict__ hist) {
  __shared__ int h[NBUCK];
  const int t = threadIdx.x;
  for (int i = t; i < NBUCK; i += 256) h[i] = 0;
  __syncthreads();
  const int e0 = blockIdx.x * 2048;
#pragma unroll
  for (int u = 0; u < 8; ++u) {
    int e = e0 + u * 256 + t;
    if (e < E_TOT) {
      int dst = (e < N_EDGES) ? ei[N_EDGES + e] : (e - N_EDGES);
      atomicAdd(&h[dst >> 9], 1);
    }
  }
  __syncthreads();
  for (int i = t; i < NBUCK; i += 256) hist[i * HSTRIDE + blockIdx.x] = h[i];
}

__global__ __launch_bounds__(1024) void k_bscan1(int* __restrict__ hist,
                                                 int* __restrict__ btot) {
  __shared__ int sh[1024];
  const int b = blockIdx.x, t = threadIdx.x;
  int v = (t < NBLK1) ? hist[b * HSTRIDE + t] : 0;
  sh[t] = v;
  __syncthreads();
  for (int off = 1; off < 1024; off <<= 1) {
    int x = (t >= off) ? sh[t - off] : 0;
    __syncthreads();
    sh[t] += x;
    __syncthreads();
  }
  if (t < NBLK1) hist[b * HSTRIDE + t] = sh[t] - v;   // exclusive
  if (t == 1023) btot[b] = sh[1023];
}

__global__ void k_bscan2(const int* __restrict__ btot, int* __restrict__ bbase) {
  if (threadIdx.x == 0 && blockIdx.x == 0) {
    int run = 0;
    for (int i = 0; i < NBUCK; ++i) { bbase[i] = run; run += btot[i]; }
    bbase[NBUCK] = run;   // == E_TOT
  }
}

__global__ __launch_bounds__(256) void k_b2(const int* __restrict__ ei,
                                            const int* __restrict__ hist,
                                            const int* __restrict__ bbase,
                                            int2* __restrict__ buf) {
  __shared__ int h[NBUCK];
  __shared__ int base2[NBUCK];
  const int t = threadIdx.x;
  for (int i = t; i < NBUCK; i += 256) {
    h[i] = 0;
    base2[i] = bbase[i] + hist[i * HSTRIDE + blockIdx.x];
  }
  __syncthreads();
  const int e0 = blockIdx.x * 2048;
#pragma unroll
  for (int u = 0; u < 8; ++u) {
    int e = e0 + u * 256 + t;
    if (e < E_TOT) {
      int src, dst;
      if (e < N_EDGES) { src = ei[e]; dst = ei[N_EDGES + e]; }
      else             { src = e - N_EDGES; dst = src; }
      int bk = dst >> 9;
      int r = atomicAdd(&h[bk], 1);
      buf[base2[bk] + r] = int2{src, dst};
    }
  }
}

__global__ __launch_bounds__(512) void k_b3(const int2* __restrict__ buf,
                                            const int* __restrict__ bbase,
                                            int* __restrict__ indptr,
                                            int* __restrict__ csr_src) {
  __shared__ int cnt[512];
  __shared__ int cur[512];
  const int b = blockIdx.x, t = threadIdx.x;
  cnt[t] = 0;
  __syncthreads();
  const int es = bbase[b], ee = bbase[b + 1];
  for (int e = es + t; e < ee; e += 512) {
    int2 p = buf[e];
    atomicAdd(&cnt[p.y & 511], 1);
  }
  __syncthreads();
  int v = cnt[t];
  cur[t] = v;
  __syncthreads();
  for (int off = 1; off < 512; off <<= 1) {
    int x = (t >= off) ? cur[t - off] : 0;
    __syncthreads();
    cur[t] += x;
    __syncthreads();
  }
  int excl = cur[t] - v;
  int n = b * 512 + t;
  if (n < N_NODES) indptr[n] = es + excl;
  if (b == NBUCK - 1 && t == 0) indptr[N_NODES] = E_TOT;
  __syncthreads();
  cur[t] = es + excl;       // running cursor
  __syncthreads();
  for (int e = es + t; e < ee; e += 512) {
    int2 p = buf[e];
    int pos = atomicAdd(&cur[p.y & 511], 1);
    csr_src[pos] = p.x;
  }
}

// -------------------------------- MFMA GEMM h = X @ W^T (+ a_s/a_d), bf16 out
template <bool IN_F32>
__global__ __launch_bounds__(256) void k_gemm(const void* __restrict__ Xin,
                                              const float* __restrict__ W,
                                              const float* __restrict__ att_s,
                                              const float* __restrict__ att_d,
                                              ushort_t* __restrict__ Hb,
                                              float* __restrict__ As,
                                              float* __restrict__ Ad) {
  __shared__ ushort_t Wl[128 * 128];  // 32 KB
  __shared__ ushort_t Xl[64 * 128];   // 16 KB (reused as epilogue stage)
  const int t = threadIdx.x;
  const int row0 = blockIdx.x * 64;

#pragma unroll
  for (int i = 0; i < 16; ++i) {
    int idx = (t + i * 256) << 2;     // float index
    int o = idx >> 7, c = idx & 127;
    float4 w = *(const float4*)&W[idx];
    ushort4 wb{f2bf(w.x), f2bf(w.y), f2bf(w.z), f2bf(w.w)};
    *(ushort4*)((char*)Wl + o * 256 + ((c * 2) ^ ((o & 7) << 4))) = wb;
  }
  if (IN_F32) {
    const float* X = (const float*)Xin;
#pragma unroll
    for (int i = 0; i < 8; ++i) {
      int idx = (t + i * 256) << 2;
      int r = idx >> 7, c = idx & 127;
      int row = row0 + r;
      float4 xv = (row < N_NODES) ? *(const float4*)&X[row * 128 + c]
                                  : float4{0.f, 0.f, 0.f, 0.f};
      ushort4 xb{f2bf(xv.x), f2bf(xv.y), f2bf(xv.z), f2bf(xv.w)};
      *(ushort4*)((char*)Xl + r * 256 + ((c * 2) ^ ((r & 7) << 4))) = xb;
    }
  } else {
    const ushort_t* X = (const ushort_t*)Xin;
#pragma unroll
    for (int i = 0; i < 4; ++i) {
      int idx = (t + i * 256) << 3;   // ushort index, 8 per iter
      int r = idx >> 7, c = idx & 127;
      int row = row0 + r;
      uint4 xv = (row < N_NODES) ? *(const uint4*)&X[row * 128 + c]
                                 : uint4{0u, 0u, 0u, 0u};
      *(uint4*)((char*)Xl + r * 256 + ((c * 2) ^ ((r & 7) << 4))) = xv;
    }
  }
  __syncthreads();

  const int wv = t >> 6;
  const int lane = t & 63;
  const int lr = lane & 15;
  const int lg = lane >> 4;
  f32x4 acc[8] = {};

#pragma unroll
  for (int ks = 0; ks < 4; ++ks) {
    const int kbyte = ks * 64 + lg * 16;
    const int arow = wv * 16 + lr;
    bf16x8 afrag = *(const bf16x8*)((char*)Xl + arow * 256 +
                                    (kbyte ^ ((arow & 7) << 4)));
#pragma unroll
    for (int ot = 0; ot < 8; ++ot) {
      const int orow = ot * 16 + lr;
      bf16x8 bfrag = *(const bf16x8*)((char*)Wl + orow * 256 +
                                      (kbyte ^ ((orow & 7) << 4)));
      acc[ot] = __builtin_amdgcn_mfma_f32_16x16x32_bf16(afrag, bfrag, acc[ot],
                                                        0, 0, 0);
    }
  }

  // fused a_s/a_d epilogue
  float ps[4] = {0.f, 0.f, 0.f, 0.f}, pd[4] = {0.f, 0.f, 0.f, 0.f};
#pragma unroll
  for (int ot = 0; ot < 8; ++ot) {
    float sa = att_s[ot * 16 + lr], sd = att_d[ot * 16 + lr];
#pragma unroll
    for (int j = 0; j < 4; ++j) {
      ps[j] += acc[ot][j] * sa;
      pd[j] += acc[ot][j] * sd;
    }
  }
#pragma unroll
  for (int m = 1; m < 16; m <<= 1) {
#pragma unroll
    for (int j = 0; j < 4; ++j) {
      ps[j] += __shfl_xor(ps[j], m);
      pd[j] += __shfl_xor(pd[j], m);
    }
  }
  if (lr == 0) {
#pragma unroll
    for (int j = 0; j < 4; ++j) {
      int row = row0 + wv * 16 + lg * 4 + j;
      if (row < N_NODES) { As[row] = ps[j]; Ad[row] = pd[j]; }
    }
  }

  // stage D tile (bf16, swizzled) in Xl, then coalesced write
  __syncthreads();
#pragma unroll
  for (int ot = 0; ot < 8; ++ot)
#pragma unroll
    for (int j = 0; j < 4; ++j) {
      int r = wv * 16 + lg * 4 + j;
      int cbyte = (ot * 16 + lr) * 2;
      *(ushort_t*)((char*)Xl + r * 256 + (cbyte ^ ((r & 7) << 4))) =
          f2bf(acc[ot][j]);
    }
  __syncthreads();
#pragma unroll
  for (int i = 0; i < 4; ++i) {
    int idx = t + i * 256;
    int r = idx >> 4, u = idx & 15;
    int row = row0 + r;
    if (row < N_NODES)
      *(uint4*)&Hb[row * 128 + u * 8] =
          *(const uint4*)((char*)Xl + r * 256 + ((u * 16) ^ ((r & 7) << 4)));
  }
}

// ------------------------------------- attention softmax + aggregation (CSR)
// TWO nodes per wave; ONE-PASS softmax: unnormalized w = exp(leaky(e)),
// gather-FMA starts immediately, single sum-reduce at the end, scale by 1/sum.
// (softmax is shift-invariant; |e| <~ 10 here so exp(e) cannot overflow f32)
__global__ __launch_bounds__(256) void k_agg(const ushort_t* __restrict__ Hb,
                                             const float* __restrict__ a_s,
                                             const float* __restrict__ a_d,
                                             const int* __restrict__ indptr,
                                             const int* __restrict__ csr_src,
                                             const float* __restrict__ bias,
                                             ushort_t* __restrict__ OUTb) {
  const int lane = threadIdx.x & 63;
  const int wid  = threadIdx.x >> 6;
  const int half = lane >> 5;
  const int l32  = lane & 31;
  const int n = blockIdx.x * 8 + wid * 2 + half;

  const int start = indptr[n];
  const int deg   = indptr[n + 1] - start;
  const float adn = a_d[n];

  // per-lane unnormalized weight for edge l32 (chunk 0)
  int   s0 = csr_src[start + ((l32 < deg) ? l32 : 0)];
  float w0 = 0.f;
  if (l32 < deg) {
    float e = a_s[s0] + adn;
    e = (e > 0.f) ? e : 0.2f * e;
    w0 = __expf(e);
  }
  float wsum = w0;

  const int degA = __shfl(deg, 0);
  const int degB = __shfl(deg, 32);
  const int degM = max(degA, degB);

  const int q  = lane >> 4;
  const int qe = q & 1;
  const int srcbase = (q >> 1) << 5;
  const int ch = (lane & 15) << 3;
  float acc8[8] = {0.f, 0.f, 0.f, 0.f, 0.f, 0.f, 0.f, 0.f};

#define FMA8(W4, A)                                                         \
  {                                                                         \
    float a_ = (A);                                                         \
    acc8[0] += a_ * __uint_as_float((W4).x << 16);                          \
    acc8[1] += a_ * __uint_as_float((W4).x & 0xFFFF0000u);                  \
    acc8[2] += a_ * __uint_as_float((W4).y << 16);                          \
    acc8[3] += a_ * __uint_as_float((W4).y & 0xFFFF0000u);                  \
    acc8[4] += a_ * __uint_as_float((W4).z << 16);                          \
    acc8[5] += a_ * __uint_as_float((W4).z & 0xFFFF0000u);                  \
    acc8[6] += a_ * __uint_as_float((W4).w << 16);                          \
    acc8[7] += a_ * __uint_as_float((W4).w & 0xFFFF0000u);                  \
  }

  for (int base = 0; base < degM; base += 32) {
    float myw;
    int mys;
    if (base == 0) {
      myw = w0;
      mys = s0;
    } else {
      int j = base + l32;
      mys = csr_src[start + ((j < deg) ? j : 0)];
      myw = 0.f;
      if (j < deg) {
        float e = a_s[mys] + adn;
        e = (e > 0.f) ? e : 0.2f * e;
        myw = __expf(e);
      }
      wsum += myw;
    }
    const int npM = (min(degM - base, 32) + 1) >> 1;
    int u0 = 0;
    for (; u0 + 4 <= npM; u0 += 4) {
      float av[4]; int sv[4]; uint4 hv[4];
#pragma unroll
      for (int u = 0; u < 4; ++u) {
        int sl = srcbase + (((u0 + u) << 1) + qe);
        av[u] = __shfl(myw, sl);
        sv[u] = __shfl(mys, sl);
      }
#pragma unroll
      for (int u = 0; u < 4; ++u)
        hv[u] = *(const uint4*)&Hb[sv[u] * 128 + ch];
#pragma unroll
      for (int u = 0; u < 4; ++u) FMA8(hv[u], av[u]);
    }
    for (; u0 < npM; ++u0) {
      int sl = srcbase + ((u0 << 1) + qe);
      float a = __shfl(myw, sl);
      int s = __shfl(mys, sl);
      uint4 hv = *(const uint4*)&Hb[s * 128 + ch];
      FMA8(hv, a);
    }
  }
#undef FMA8

  // deferred softmax denominator: reduce within the 32-lane half
#pragma unroll
  for (int m = 1; m < 32; m <<= 1) wsum += __shfl_xor(wsum, m);
  const float inv = 1.0f / wsum;

  // combine quarter pairs, normalize
#pragma unroll
  for (int c = 0; c < 8; ++c)
    acc8[c] = (acc8[c] + __shfl_xor(acc8[c], 16)) * inv;

  if (qe == 0) {
    float4 b0 = *(const float4*)&bias[ch];
    float4 b1 = *(const float4*)&bias[ch + 4];
    ushort4 lo{f2bf(fmaxf(acc8[0] + b0.x, 0.f)),
               f2bf(fmaxf(acc8[1] + b0.y, 0.f)),
               f2bf(fmaxf(acc8[2] + b0.z, 0.f)),
               f2bf(fmaxf(acc8[3] + b0.w, 0.f))};
    ushort4 hi{f2bf(fmaxf(acc8[4] + b1.x, 0.f)),
               f2bf(fmaxf(acc8[5] + b1.y, 0.f)),
               f2bf(fmaxf(acc8[6] + b1.z, 0.f)),
               f2bf(fmaxf(acc8[7] + b1.w, 0.f))};
    *(ushort4*)&OUTb[n * 128 + ch] = lo;
    *(ushort4*)&OUTb[n * 128 + ch + 4] = hi;
  }
}

// ---------------------------------------------- head (128->8, tanh), bf16 in
__global__ __launch_bounds__(256) void k_head(const ushort_t* __restrict__ Hb,
                                              const float* __restrict__ Wl,
                                              const float* __restrict__ bl,
                                              float* __restrict__ h8) {
  __shared__ float Wls[8][128];
  int t = threadIdx.x;
#pragma unroll
  for (int i = 0; i < 4; ++i) {
    int idx = t + i * 256;
    Wls[idx >> 7][idx & 127] = Wl[idx];
  }
  __syncthreads();

  int n = blockIdx.x * 4 + (t >> 6);
  if (n >= N_NODES) return;
  int lane = t & 63;
  uint_t hv = *(const uint_t*)&Hb[n * 128 + 2 * lane];
  float hx = __uint_as_float((hv & 0xFFFFu) << 16);
  float hy = __uint_as_float(hv & 0xFFFF0000u);
  float mine = 0.f;
#pragma unroll
  for (int a = 0; a < 8; ++a) {
    float2 wv = *(const float2*)&Wls[a][2 * lane];
    float v = hx * wv.x + hy * wv.y;
#pragma unroll
    for (int m = 1; m < 64; m <<= 1) v += __shfl_xor(v, m);
    if (lane == a) mine = v;
  }
  if (lane < 8) h8[n * 8 + lane] = tanhf(mine + bl[lane]);
}

// ------------------------------------ mean pool: one block per graph
__global__ __launch_bounds__(256) void k_pool(const float* __restrict__ h8,
                                              const int* __restrict__ batch,
                                              float* __restrict__ out) {
  int g = blockIdx.x;
  __shared__ int bounds[2];
  if (threadIdx.x < 2) {
    int target = g + threadIdx.x;
    int lo = 0, hi = N_NODES;
    while (lo < hi) {
      int mid = (lo + hi) >> 1;
      if (batch[mid] < target) lo = mid + 1; else hi = mid;
    }
    bounds[threadIdx.x] = lo;
  }
  __syncthreads();
  int lo = bounds[0], hi = bounds[1];
  int ch = threadIdx.x & 7;
  float acc = 0.f;
  for (int n = lo + (threadIdx.x >> 3); n < hi; n += 32)
    acc += h8[n * 8 + ch];

  __shared__ float red[256];
  red[threadIdx.x] = acc;
  __syncthreads();
  for (int off = 128; off >= 8; off >>= 1) {
    if (threadIdx.x < off) red[threadIdx.x] += red[threadIdx.x + off];
    __syncthreads();
  }
  if (threadIdx.x < 8)
    out[g * 8 + threadIdx.x] = red[threadIdx.x] / fmaxf((float)(hi - lo), 1.0f);
}

// ---------------------------------------------------------------- launcher
extern "C" void kernel_launch(void* const* d_in, const int* in_sizes, int n_in,
                              void* d_out, int out_size, void* d_ws, size_t ws_size,
                              hipStream_t stream) {
  const float* x   = (const float*)d_in[0];
  const int*   ei  = (const int*)d_in[1];
  const int*   bat = (const int*)d_in[2];
  const float* Wm[3]  = {(const float*)d_in[3],  (const float*)d_in[7],  (const float*)d_in[11]};
  const float* asv[3] = {(const float*)d_in[4],  (const float*)d_in[8],  (const float*)d_in[12]};
  const float* adv[3] = {(const float*)d_in[5],  (const float*)d_in[9],  (const float*)d_in[13]};
  const float* bv[3]  = {(const float*)d_in[6],  (const float*)d_in[10], (const float*)d_in[14]};
  const float* Wl  = (const float*)d_in[15];
  const float* bl  = (const float*)d_in[16];
  float* out = (float*)d_out;

  char* w = (char*)d_ws;
  ushort_t* Hb   = (ushort_t*)(w + 0);         // 25,600,000 B (gemm out, bf16)
  ushort_t* hB2  = (ushort_t*)(w + 25600000);  // 25,600,000 B (agg out, bf16)
  float* a_s     = (float*)(w + 51200000);     // 400,000 B
  float* a_d     = (float*)(w + 51600000);     // 400,000 B
  int*   indptr  = (int*)  (w + 52000000);     // 400,128 B
  int*   csr     = (int*)  (w + 52400128);     // 6,800,000 B
  int2*  buf1    = (int2*) (w + 59200128);     // 13,600,000 B
  int*   hist    = (int*)  (w + 72800128);     // 652,288 B (196 x 832)
  int*   btot    = (int*)  (w + 73452416);     // 784 B
  int*   bbase   = (int*)  (w + 73453200);     // 788 B
  float* h8      = (float*)(w + 73454000);     // 3,200,000 B

  const int gblk = (N_NODES + 63) / 64;
  const int ablk = N_NODES / 8;   // 2 nodes per wave, 8 per block

  // CSR build (bucket sort, LDS atomics only)
  k_b1    <<<NBLK1, 256, 0, stream>>>(ei, hist);
  k_bscan1<<<NBUCK, 1024, 0, stream>>>(hist, btot);
  k_bscan2<<<1, 64, 0, stream>>>(btot, bbase);
  k_b2    <<<NBLK1, 256, 0, stream>>>(ei, hist, bbase, buf1);
  k_b3    <<<NBUCK, 512, 0, stream>>>(buf1, bbase, indptr, csr);

  k_gemm<true><<<gblk, 256, 0, stream>>>(x, Wm[0], asv[0], adv[0], Hb, a_s, a_d);
  k_agg<<<ablk, 256, 0, stream>>>(Hb, a_s, a_d, indptr, csr, bv[0], hB2);
  for (int l = 1; l < 3; ++l) {
    k_gemm<false><<<gblk, 256, 0, stream>>>(hB2, Wm[l], asv[l], adv[l], Hb,
                                            a_s, a_d);
    k_agg<<<ablk, 256, 0, stream>>>(Hb, a_s, a_d, indptr, csr, bv[l], hB2);
  }

  k_head<<<N_NODES / 4, 256, 0, stream>>>(hB2, Wl, bl, h8);
  k_pool<<<NGRAPH, 256, 0, stream>>>(h8, bat, out);
}

// Round 13
// 312.428 us; speedup vs baseline: 1.5006x; 1.1626x over previous
//
#include <hip/hip_runtime.h>

#define N_NODES 100000
#define N_EDGES 1600000
#define E_TOT   1700000
#define HID     128
#define NGRAPH  256
#define NBUCK   196      // ceil(100000/512)
#define NBLK1   831      // ceil(1700000/2048)
#define HSTRIDE 832

typedef unsigned short ushort_t;
typedef unsigned int uint_t;
typedef __attribute__((ext_vector_type(8))) short bf16x8;
typedef __attribute__((ext_vector_type(4))) float f32x4;

__device__ inline ushort_t f2bf(float f) {   // RNE pack
  uint_t u = __float_as_uint(f);
  return (ushort_t)((u + 0x7FFFu + ((u >> 16) & 1u)) >> 16);
}

// --------------------------- CSR build: 2-level LDS bucket sort, no global atomics
__global__ __launch_bounds__(256) void k_b1(const int* __restrict__ ei,
                                            int* __restrict__ hist) {
  __shared__ int h[NBUCK];
  const int t = threadIdx.x;
  for (int i = t; i < NBUCK; i += 256) h[i] = 0;
  __syncthreads();
  const int e0 = blockIdx.x * 2048;
#pragma unroll
  for (int u = 0; u < 8; ++u) {
    int e = e0 + u * 256 + t;
    if (e < E_TOT) {
      int dst = (e < N_EDGES) ? ei[N_EDGES + e] : (e - N_EDGES);
      atomicAdd(&h[dst >> 9], 1);
    }
  }
  __syncthreads();
  for (int i = t; i < NBUCK; i += 256) hist[i * HSTRIDE + blockIdx.x] = h[i];
}

__global__ __launch_bounds__(1024) void k_bscan1(int* __restrict__ hist,
                                                 int* __restrict__ btot) {
  __shared__ int sh[1024];
  const int b = blockIdx.x, t = threadIdx.x;
  int v = (t < NBLK1) ? hist[b * HSTRIDE + t] : 0;
  sh[t] = v;
  __syncthreads();
  for (int off = 1; off < 1024; off <<= 1) {
    int x = (t >= off) ? sh[t - off] : 0;
    __syncthreads();
    sh[t] += x;
    __syncthreads();
  }
  if (t < NBLK1) hist[b * HSTRIDE + t] = sh[t] - v;   // exclusive
  if (t == 1023) btot[b] = sh[1023];
}

__global__ void k_bscan2(const int* __restrict__ btot, int* __restrict__ bbase) {
  if (threadIdx.x == 0 && blockIdx.x == 0) {
    int run = 0;
    for (int i = 0; i < NBUCK; ++i) { bbase[i] = run; run += btot[i]; }
    bbase[NBUCK] = run;   // == E_TOT
  }
}

__global__ __launch_bounds__(256) void k_b2(const int* __restrict__ ei,
                                            const int* __restrict__ hist,
                                            const int* __restrict__ bbase,
                                            int2* __restrict__ buf) {
  __shared__ int h[NBUCK];
  __shared__ int base2[NBUCK];
  const int t = threadIdx.x;
  for (int i = t; i < NBUCK; i += 256) {
    h[i] = 0;
    base2[i] = bbase[i] + hist[i * HSTRIDE + blockIdx.x];
  }
  __syncthreads();
  const int e0 = blockIdx.x * 2048;
#pragma unroll
  for (int u = 0; u < 8; ++u) {
    int e = e0 + u * 256 + t;
    if (e < E_TOT) {
      int src, dst;
      if (e < N_EDGES) { src = ei[e]; dst = ei[N_EDGES + e]; }
      else             { src = e - N_EDGES; dst = src; }
      int bk = dst >> 9;
      int r = atomicAdd(&h[bk], 1);
      buf[base2[bk] + r] = int2{src, dst};
    }
  }
}

__global__ __launch_bounds__(512) void k_b3(const int2* __restrict__ buf,
                                            const int* __restrict__ bbase,
                                            int* __restrict__ indptr,
                                            int* __restrict__ csr_src) {
  __shared__ int cnt[512];
  __shared__ int cur[512];
  const int b = blockIdx.x, t = threadIdx.x;
  cnt[t] = 0;
  __syncthreads();
  const int es = bbase[b], ee = bbase[b + 1];
  for (int e = es + t; e < ee; e += 512) {
    int2 p = buf[e];
    atomicAdd(&cnt[p.y & 511], 1);
  }
  __syncthreads();
  int v = cnt[t];
  cur[t] = v;
  __syncthreads();
  for (int off = 1; off < 512; off <<= 1) {
    int x = (t >= off) ? cur[t - off] : 0;
    __syncthreads();
    cur[t] += x;
    __syncthreads();
  }
  int excl = cur[t] - v;
  int n = b * 512 + t;
  if (n < N_NODES) indptr[n] = es + excl;
  if (b == NBUCK - 1 && t == 0) indptr[N_NODES] = E_TOT;
  __syncthreads();
  cur[t] = es + excl;       // running cursor
  __syncthreads();
  for (int e = es + t; e < ee; e += 512) {
    int2 p = buf[e];
    int pos = atomicAdd(&cur[p.y & 511], 1);
    csr_src[pos] = p.x;
  }
}

// -------------------------------- MFMA GEMM h = X @ W^T (+ a_s/a_d), bf16 out
template <bool IN_F32>
__global__ __launch_bounds__(256) void k_gemm(const void* __restrict__ Xin,
                                              const float* __restrict__ W,
                                              const float* __restrict__ att_s,
                                              const float* __restrict__ att_d,
                                              ushort_t* __restrict__ Hb,
                                              float* __restrict__ As,
                                              float* __restrict__ Ad) {
  __shared__ ushort_t Wl[128 * 128];  // 32 KB
  __shared__ ushort_t Xl[64 * 128];   // 16 KB (reused as epilogue stage)
  const int t = threadIdx.x;
  const int row0 = blockIdx.x * 64;

#pragma unroll
  for (int i = 0; i < 16; ++i) {
    int idx = (t + i * 256) << 2;     // float index
    int o = idx >> 7, c = idx & 127;
    float4 w = *(const float4*)&W[idx];
    ushort4 wb{f2bf(w.x), f2bf(w.y), f2bf(w.z), f2bf(w.w)};
    *(ushort4*)((char*)Wl + o * 256 + ((c * 2) ^ ((o & 7) << 4))) = wb;
  }
  if (IN_F32) {
    const float* X = (const float*)Xin;
#pragma unroll
    for (int i = 0; i < 8; ++i) {
      int idx = (t + i * 256) << 2;
      int r = idx >> 7, c = idx & 127;
      int row = row0 + r;
      float4 xv = (row < N_NODES) ? *(const float4*)&X[row * 128 + c]
                                  : float4{0.f, 0.f, 0.f, 0.f};
      ushort4 xb{f2bf(xv.x), f2bf(xv.y), f2bf(xv.z), f2bf(xv.w)};
      *(ushort4*)((char*)Xl + r * 256 + ((c * 2) ^ ((r & 7) << 4))) = xb;
    }
  } else {
    const ushort_t* X = (const ushort_t*)Xin;
#pragma unroll
    for (int i = 0; i < 4; ++i) {
      int idx = (t + i * 256) << 3;   // ushort index, 8 per iter
      int r = idx >> 7, c = idx & 127;
      int row = row0 + r;
      uint4 xv = (row < N_NODES) ? *(const uint4*)&X[row * 128 + c]
                                 : uint4{0u, 0u, 0u, 0u};
      *(uint4*)((char*)Xl + r * 256 + ((c * 2) ^ ((r & 7) << 4))) = xv;
    }
  }
  __syncthreads();

  const int wv = t >> 6;
  const int lane = t & 63;
  const int lr = lane & 15;
  const int lg = lane >> 4;
  f32x4 acc[8] = {};

#pragma unroll
  for (int ks = 0; ks < 4; ++ks) {
    const int kbyte = ks * 64 + lg * 16;
    const int arow = wv * 16 + lr;
    bf16x8 afrag = *(const bf16x8*)((char*)Xl + arow * 256 +
                                    (kbyte ^ ((arow & 7) << 4)));
#pragma unroll
    for (int ot = 0; ot < 8; ++ot) {
      const int orow = ot * 16 + lr;
      bf16x8 bfrag = *(const bf16x8*)((char*)Wl + orow * 256 +
                                      (kbyte ^ ((orow & 7) << 4)));
      acc[ot] = __builtin_amdgcn_mfma_f32_16x16x32_bf16(afrag, bfrag, acc[ot],
                                                        0, 0, 0);
    }
  }

  // fused a_s/a_d epilogue
  float ps[4] = {0.f, 0.f, 0.f, 0.f}, pd[4] = {0.f, 0.f, 0.f, 0.f};
#pragma unroll
  for (int ot = 0; ot < 8; ++ot) {
    float sa = att_s[ot * 16 + lr], sd = att_d[ot * 16 + lr];
#pragma unroll
    for (int j = 0; j < 4; ++j) {
      ps[j] += acc[ot][j] * sa;
      pd[j] += acc[ot][j] * sd;
    }
  }
#pragma unroll
  for (int m = 1; m < 16; m <<= 1) {
#pragma unroll
    for (int j = 0; j < 4; ++j) {
      ps[j] += __shfl_xor(ps[j], m);
      pd[j] += __shfl_xor(pd[j], m);
    }
  }
  if (lr == 0) {
#pragma unroll
    for (int j = 0; j < 4; ++j) {
      int row = row0 + wv * 16 + lg * 4 + j;
      if (row < N_NODES) { As[row] = ps[j]; Ad[row] = pd[j]; }
    }
  }

  // stage D tile (bf16, swizzled) in Xl, then coalesced write
  __syncthreads();
#pragma unroll
  for (int ot = 0; ot < 8; ++ot)
#pragma unroll
    for (int j = 0; j < 4; ++j) {
      int r = wv * 16 + lg * 4 + j;
      int cbyte = (ot * 16 + lr) * 2;
      *(ushort_t*)((char*)Xl + r * 256 + (cbyte ^ ((r & 7) << 4))) =
          f2bf(acc[ot][j]);
    }
  __syncthreads();
#pragma unroll
  for (int i = 0; i < 4; ++i) {
    int idx = t + i * 256;
    int r = idx >> 4, u = idx & 15;
    int row = row0 + r;
    if (row < N_NODES)
      *(uint4*)&Hb[row * 128 + u * 8] =
          *(const uint4*)((char*)Xl + r * 256 + ((u * 16) ^ ((r & 7) << 4)));
  }
}

// ------------------------------------- attention softmax + aggregation (CSR)
// TWO nodes per wave; ONE-PASS softmax (unnormalized, deferred denominator)
__global__ __launch_bounds__(256) void k_agg(const ushort_t* __restrict__ Hb,
                                             const float* __restrict__ a_s,
                                             const float* __restrict__ a_d,
                                             const int* __restrict__ indptr,
                                             const int* __restrict__ csr_src,
                                             const float* __restrict__ bias,
                                             ushort_t* __restrict__ OUTb) {
  const int lane = threadIdx.x & 63;
  const int wid  = threadIdx.x >> 6;
  const int half = lane >> 5;
  const int l32  = lane & 31;
  const int n = blockIdx.x * 8 + wid * 2 + half;

  const int start = indptr[n];
  const int deg   = indptr[n + 1] - start;
  const float adn = a_d[n];

  int   s0 = csr_src[start + ((l32 < deg) ? l32 : 0)];
  float w0 = 0.f;
  if (l32 < deg) {
    float e = a_s[s0] + adn;
    e = (e > 0.f) ? e : 0.2f * e;
    w0 = __expf(e);
  }
  float wsum = w0;

  const int degA = __shfl(deg, 0);
  const int degB = __shfl(deg, 32);
  const int degM = max(degA, degB);

  const int q  = lane >> 4;
  const int qe = q & 1;
  const int srcbase = (q >> 1) << 5;
  const int ch = (lane & 15) << 3;
  float acc8[8] = {0.f, 0.f, 0.f, 0.f, 0.f, 0.f, 0.f, 0.f};

#define FMA8(W4, A)                                                         \
  {                                                                         \
    float a_ = (A);                                                         \
    acc8[0] += a_ * __uint_as_float((W4).x << 16);                          \
    acc8[1] += a_ * __uint_as_float((W4).x & 0xFFFF0000u);                  \
    acc8[2] += a_ * __uint_as_float((W4).y << 16);                          \
    acc8[3] += a_ * __uint_as_float((W4).y & 0xFFFF0000u);                  \
    acc8[4] += a_ * __uint_as_float((W4).z << 16);                          \
    acc8[5] += a_ * __uint_as_float((W4).z & 0xFFFF0000u);                  \
    acc8[6] += a_ * __uint_as_float((W4).w << 16);                          \
    acc8[7] += a_ * __uint_as_float((W4).w & 0xFFFF0000u);                  \
  }

  for (int base = 0; base < degM; base += 32) {
    float myw;
    int mys;
    if (base == 0) {
      myw = w0;
      mys = s0;
    } else {
      int j = base + l32;
      mys = csr_src[start + ((j < deg) ? j : 0)];
      myw = 0.f;
      if (j < deg) {
        float e = a_s[mys] + adn;
        e = (e > 0.f) ? e : 0.2f * e;
        myw = __expf(e);
      }
      wsum += myw;
    }
    const int npM = (min(degM - base, 32) + 1) >> 1;
    int u0 = 0;
    for (; u0 + 4 <= npM; u0 += 4) {
      float av[4]; int sv[4]; uint4 hv[4];
#pragma unroll
      for (int u = 0; u < 4; ++u) {
        int sl = srcbase + (((u0 + u) << 1) + qe);
        av[u] = __shfl(myw, sl);
        sv[u] = __shfl(mys, sl);
      }
#pragma unroll
      for (int u = 0; u < 4; ++u)
        hv[u] = *(const uint4*)&Hb[sv[u] * 128 + ch];
#pragma unroll
      for (int u = 0; u < 4; ++u) FMA8(hv[u], av[u]);
    }
    for (; u0 < npM; ++u0) {
      int sl = srcbase + ((u0 << 1) + qe);
      float a = __shfl(myw, sl);
      int s = __shfl(mys, sl);
      uint4 hv = *(const uint4*)&Hb[s * 128 + ch];
      FMA8(hv, a);
    }
  }
#undef FMA8

#pragma unroll
  for (int m = 1; m < 32; m <<= 1) wsum += __shfl_xor(wsum, m);
  const float inv = 1.0f / wsum;

#pragma unroll
  for (int c = 0; c < 8; ++c)
    acc8[c] = (acc8[c] + __shfl_xor(acc8[c], 16)) * inv;

  if (qe == 0) {
    float4 b0 = *(const float4*)&bias[ch];
    float4 b1 = *(const float4*)&bias[ch + 4];
    ushort4 lo{f2bf(fmaxf(acc8[0] + b0.x, 0.f)),
               f2bf(fmaxf(acc8[1] + b0.y, 0.f)),
               f2bf(fmaxf(acc8[2] + b0.z, 0.f)),
               f2bf(fmaxf(acc8[3] + b0.w, 0.f))};
    ushort4 hi{f2bf(fmaxf(acc8[4] + b1.x, 0.f)),
               f2bf(fmaxf(acc8[5] + b1.y, 0.f)),
               f2bf(fmaxf(acc8[6] + b1.z, 0.f)),
               f2bf(fmaxf(acc8[7] + b1.w, 0.f))};
    *(ushort4*)&OUTb[n * 128 + ch] = lo;
    *(ushort4*)&OUTb[n * 128 + ch + 4] = hi;
  }
}

// ---------------------- head (128->8, tanh) via MFMA: no shuffle-reduce chain
__global__ __launch_bounds__(256) void k_head(const ushort_t* __restrict__ Hb,
                                              const float* __restrict__ Wlh,
                                              const float* __restrict__ bl,
                                              float* __restrict__ h8) {
  __shared__ ushort_t Xl[64 * 128];   // 16 KB
  __shared__ ushort_t Wls[16 * 128];  // 4 KB (rows 8..15 zero)
  const int t = threadIdx.x;
  const int row0 = blockIdx.x * 64;

  // stage W' (8x128 f32 -> 16x128 bf16 zero-padded, swizzled): 8 elems/thread
  {
    int idx = t * 8;
    int o = idx >> 7, c = idx & 127;
    ushort4 wa{0, 0, 0, 0}, wb{0, 0, 0, 0};
    if (o < 8) {
      float4 w0 = *(const float4*)&Wlh[o * 128 + c];
      float4 w1 = *(const float4*)&Wlh[o * 128 + c + 4];
      wa = ushort4{f2bf(w0.x), f2bf(w0.y), f2bf(w0.z), f2bf(w0.w)};
      wb = ushort4{f2bf(w1.x), f2bf(w1.y), f2bf(w1.z), f2bf(w1.w)};
    }
    *(ushort4*)((char*)Wls + o * 256 + ((c * 2) ^ ((o & 7) << 4))) = wa;
    *(ushort4*)((char*)Wls + o * 256 + (((c + 4) * 2) ^ ((o & 7) << 4))) = wb;
  }
  // stage hB2 tile (bf16, swizzled)
#pragma unroll
  for (int i = 0; i < 4; ++i) {
    int idx = (t + i * 256) << 3;
    int r = idx >> 7, c = idx & 127;
    int row = row0 + r;
    uint4 xv = (row < N_NODES) ? *(const uint4*)&Hb[row * 128 + c]
                               : uint4{0u, 0u, 0u, 0u};
    *(uint4*)((char*)Xl + r * 256 + ((c * 2) ^ ((r & 7) << 4))) = xv;
  }
  __syncthreads();

  const int wv = t >> 6;
  const int lane = t & 63;
  const int lr = lane & 15;
  const int lg = lane >> 4;
  f32x4 acc = {};
#pragma unroll
  for (int ks = 0; ks < 4; ++ks) {
    const int kbyte = ks * 64 + lg * 16;
    const int arow = wv * 16 + lr;
    bf16x8 afrag = *(const bf16x8*)((char*)Xl + arow * 256 +
                                    (kbyte ^ ((arow & 7) << 4)));
    bf16x8 bfrag = *(const bf16x8*)((char*)Wls + lr * 256 +
                                    (kbyte ^ ((lr & 7) << 4)));
    acc = __builtin_amdgcn_mfma_f32_16x16x32_bf16(afrag, bfrag, acc, 0, 0, 0);
  }

  if (lr < 8) {
    float b = bl[lr];
#pragma unroll
    for (int j = 0; j < 4; ++j) {
      int row = row0 + wv * 16 + lg * 4 + j;
      if (row < N_NODES) h8[row * 8 + lr] = tanhf(acc[j] + b);
    }
  }
}

// ------------------------------------ mean pool: one block per graph
__global__ __launch_bounds__(256) void k_pool(const float* __restrict__ h8,
                                              const int* __restrict__ batch,
                                              float* __restrict__ out) {
  int g = blockIdx.x;
  __shared__ int bounds[2];
  if (threadIdx.x < 2) {
    int target = g + threadIdx.x;
    int lo = 0, hi = N_NODES;
    while (lo < hi) {
      int mid = (lo + hi) >> 1;
      if (batch[mid] < target) lo = mid + 1; else hi = mid;
    }
    bounds[threadIdx.x] = lo;
  }
  __syncthreads();
  int lo = bounds[0], hi = bounds[1];
  int ch = threadIdx.x & 7;
  float acc = 0.f;
  for (int n = lo + (threadIdx.x >> 3); n < hi; n += 32)
    acc += h8[n * 8 + ch];

  __shared__ float red[256];
  red[threadIdx.x] = acc;
  __syncthreads();
  for (int off = 128; off >= 8; off >>= 1) {
    if (threadIdx.x < off) red[threadIdx.x] += red[threadIdx.x + off];
    __syncthreads();
  }
  if (threadIdx.x < 8)
    out[g * 8 + threadIdx.x] = red[threadIdx.x] / fmaxf((float)(hi - lo), 1.0f);
}

// ---------------------------------------------------------------- launcher
extern "C" void kernel_launch(void* const* d_in, const int* in_sizes, int n_in,
                              void* d_out, int out_size, void* d_ws, size_t ws_size,
                              hipStream_t stream) {
  const float* x   = (const float*)d_in[0];
  const int*   ei  = (const int*)d_in[1];
  const int*   bat = (const int*)d_in[2];
  const float* Wm[3]  = {(const float*)d_in[3],  (const float*)d_in[7],  (const float*)d_in[11]};
  const float* asv[3] = {(const float*)d_in[4],  (const float*)d_in[8],  (const float*)d_in[12]};
  const float* adv[3] = {(const float*)d_in[5],  (const float*)d_in[9],  (const float*)d_in[13]};
  const float* bv[3]  = {(const float*)d_in[6],  (const float*)d_in[10], (const float*)d_in[14]};
  const float* Wl  = (const float*)d_in[15];
  const float* bl  = (const float*)d_in[16];
  float* out = (float*)d_out;

  char* w = (char*)d_ws;
  ushort_t* Hb   = (ushort_t*)(w + 0);         // 25,600,000 B (gemm out, bf16)
  ushort_t* hB2  = (ushort_t*)(w + 25600000);  // 25,600,000 B (agg out, bf16)
  float* a_s     = (float*)(w + 51200000);     // 400,000 B
  float* a_d     = (float*)(w + 51600000);     // 400,000 B
  int*   indptr  = (int*)  (w + 52000000);     // 400,128 B
  int*   csr     = (int*)  (w + 52400128);     // 6,800,000 B
  int2*  buf1    = (int2*) (w + 59200128);     // 13,600,000 B
  int*   hist    = (int*)  (w + 72800128);     // 652,288 B (196 x 832)
  int*   btot    = (int*)  (w + 73452416);     // 784 B
  int*   bbase   = (int*)  (w + 73453200);     // 788 B
  float* h8      = (float*)(w + 73454000);     // 3,200,000 B

  const int gblk = (N_NODES + 63) / 64;
  const int ablk = N_NODES / 8;   // 2 nodes per wave, 8 per block

  // CSR build (bucket sort, LDS atomics only)
  k_b1    <<<NBLK1, 256, 0, stream>>>(ei, hist);
  k_bscan1<<<NBUCK, 1024, 0, stream>>>(hist, btot);
  k_bscan2<<<1, 64, 0, stream>>>(btot, bbase);
  k_b2    <<<NBLK1, 256, 0, stream>>>(ei, hist, bbase, buf1);
  k_b3    <<<NBUCK, 512, 0, stream>>>(buf1, bbase, indptr, csr);

  k_gemm<true><<<gblk, 256, 0, stream>>>(x, Wm[0], asv[0], adv[0], Hb, a_s, a_d);
  k_agg<<<ablk, 256, 0, stream>>>(Hb, a_s, a_d, indptr, csr, bv[0], hB2);
  for (int l = 1; l < 3; ++l) {
    k_gemm<false><<<gblk, 256, 0, stream>>>(hB2, Wm[l], asv[l], adv[l], Hb,
                                            a_s, a_d);
    k_agg<<<ablk, 256, 0, stream>>>(Hb, a_s, a_d, indptr, csr, bv[l], hB2);
  }

  k_head<<<gblk, 256, 0, stream>>>(hB2, Wl, bl, h8);
  k_pool<<<NGRAPH, 256, 0, stream>>>(h8, bat, out);
}